// Round 3
// baseline (214.181 us; speedup 1.0000x reference)
//
#include <hip/hip_runtime.h>

// pyramid_roi_align (Mask R-CNN), MI355X.
// R5b: resubmit of R5 (previous round failed at container acquire, not in the
// kernel). Design: R4's LDS staging was right about TA cost (R3 = 25.1M
// divergent lane-loads = 40.9us predicted, 40.8 measured) but had no pipeline
// (32 drain-barriers/block -> 63us). R5 rebuilds it: double-buffered LDS, ONE
// barrier per group, depth-1 register prefetch issued before the barrier so
// global latency hides under barrier+compute, and 4 blocks/box (64ch each ->
// 4000 blocks) for cross-block overlap. Wide-window boxes (~9%) keep the
// proven R3 gather fallback.

#define POOL 7
#define NCH  256
#define ELEMS_PER_BOX (NCH * POOL * POOL)    // 12544
#define QCH 64                               // channels per block
#define QELEMS (QCH * POOL * POOL)           // 3136
#define CG 8                                 // channels per staging group
#define NGROUPS (QCH / CG)                   // 8
#define ROWS 14                              // 2 rows (y0,y1) per py
#define SA 32                                // max staged window width (floats)
#define SROW 36                              // padded row stride (144B, 16B-aligned)
#define BUFSZ (CG * ROWS * SROW)             // 4032 floats = 16128 B
#define GROUP_OUT (CG * 49)                  // 392 outputs per group

typedef float f2 __attribute__((ext_vector_type(2)));
typedef float f4 __attribute__((ext_vector_type(4)));

__global__ __launch_bounds__(256, 4) void roi_align_kernel(
    const float* __restrict__ boxes,
    const float* __restrict__ p2, const float* __restrict__ p3,
    const float* __restrict__ p4, const float* __restrict__ p5,
    float* __restrict__ out, int N)
{
    const int bid  = blockIdx.x;
    const int n    = bid >> 2;      // box
    const int quarter = bid & 3;    // channel quarter: [64q, 64q+64)

    __shared__ float s_stage[2][BUFSZ];           // 32256 B
    __shared__ float s_a[49], s_b[49], s_w0[49], s_w1[49];
    __shared__ int   s_dx[49];                    // xb - xb0 (float idx in window)
    __shared__ int   s_off0[49], s_off1[49];      // fallback gather offsets
    __shared__ int   s_rowoff[ROWS];              // y*W for the 14 rows
    __shared__ int   s_HW, s_xb0, s_sa4, s_fast;
    __shared__ const float* s_fmap;

    const int tid = threadIdx.x;

    if (tid < 49) {
        const float by1 = boxes[4 * n + 0];
        const float bx1 = boxes[4 * n + 1];
        const float by2 = boxes[4 * n + 2];
        const float bx2 = boxes[4 * n + 3];
        const float h = by2 - by1;
        const float w = bx2 - bx1;
        float rl = 4.0f + log2f(sqrtf(h * w) / 0.21875f);
        int level = (int)rintf(rl);            // round-half-even = jnp.round
        level = min(5, max(2, level));
        const int H = 256 >> (level - 2);
        const int W = H;
        const int py = tid / 7;
        const int px = tid - 7 * py;

        // y interp
        const float ty = (float)py / 6.0f;
        const float ys = (by1 + ty * (by2 - by1)) * (float)(H - 1);
        const float yf = floorf(ys);
        const float ly = ys - yf;
        int y0 = (int)yf; y0 = min(H - 1, max(0, y0));
        const int y1 = min(H - 1, y0 + 1);
        const float vy = (ys >= 0.0f && ys <= (float)(H - 1)) ? 1.0f : 0.0f;

        // x interp
        const float tx = (float)px / 6.0f;
        const float xs = (bx1 + tx * (bx2 - bx1)) * (float)(W - 1);
        const float xf = floorf(xs);
        const float lx = xs - xf;
        int x0 = (int)xf; x0 = min(W - 1, max(0, x0));
        const float vx = (xs >= 0.0f && xs <= (float)(W - 1)) ? 1.0f : 0.0f;
        const int xb = min(x0, W - 2);         // float2 base column
        const bool edge = (x0 != xb);
        const float a = edge ? 0.0f : vx * (1.0f - lx);
        const float b = edge ? vx : vx * lx;

        // column window endpoints: recompute with the SAME expressions (tx=0,1)
        // so every thread derives identical xb0/sa4/fast deterministically.
        const float xsA = bx1 * (float)(W - 1);
        int xA = (int)floorf(xsA); xA = min(W - 1, max(0, xA));
        const int xbA = min(xA, W - 2);
        const float xsB = bx2 * (float)(W - 1);
        int xB = (int)floorf(xsB); xB = min(W - 1, max(0, xB));
        const int xbB = min(xB, W - 2);
        const int xb0 = xbA & ~3;                 // 16B-aligned window start
        const int sa4 = ((xbB + 2 - xb0) + 3) >> 2;   // float4s per row
        // xb0%4==0 and W%4==0 => xb0+4*sa4 <= W (no overrun past row/plane)

        s_off0[tid] = y0 * W + xb;
        s_off1[tid] = y1 * W + xb;
        s_a[tid] = a;
        s_b[tid] = b;
        s_w0[tid] = vy * (1.0f - ly);
        s_w1[tid] = vy * ly;
        s_dx[tid] = xb - xb0;
        if (px == 0) {
            s_rowoff[2 * py]     = y0 * W;
            s_rowoff[2 * py + 1] = y1 * W;
        }
        if (tid == 0) {
            s_HW = H * W;
            s_fmap = (level == 2) ? p2 : (level == 3) ? p3 : (level == 4) ? p4 : p5;
            s_xb0 = xb0;
            s_sa4 = sa4;
            s_fast = (sa4 <= (SA / 4)) ? 1 : 0;
        }
    }
    __syncthreads();

    const int HW = s_HW;
    const float* __restrict__ fbase = s_fmap + (size_t)(quarter * QCH) * HW;
    float* __restrict__ op = out + (size_t)n * ELEMS_PER_BOX + quarter * QELEMS;

    // two output slots per thread per group (392 = 256 + 136)
    const int c1  = tid / 49,  p1  = tid - 49 * c1;
    const int o2  = 256 + tid;
    const int c2  = o2 / 49,   p2i = o2 - 49 * c2;
    const bool act2 = (tid < GROUP_OUT - 256);

    const float a1 = s_a[p1],  b1 = s_b[p1],  w01 = s_w0[p1],  w11 = s_w1[p1];
    const float a2 = s_a[p2i], b2 = s_b[p2i], w02 = s_w0[p2i], w12 = s_w1[p2i];

    if (s_fast) {
        const int sa4 = s_sa4;
        const int xb0 = s_xb0;

        // staging slots: flat idx -> (rid = row slot 0..111, q = float4 col 0..7)
        int goff[4], lw[4];
        bool gact[4];
#pragma unroll
        for (int pp = 0; pp < 4; ++pp) {
            const int idx = pp * 256 + tid;
            const int rid = idx >> 3;
            const int q   = idx & 7;
            gact[pp] = (rid < CG * ROWS) && (q < sa4);
            const int cl = rid / 14;
            const int r  = rid - 14 * cl;
            lw[pp]   = rid * SROW + q * 4;                      // float idx in LDS
            goff[pp] = cl * HW + s_rowoff[r] + xb0 + q * 4;     // float idx in plane
        }

        // per-thread tap bases (constant across groups)
        const int t1 = (c1 * ROWS + 2 * (p1 / 7)) * SROW + s_dx[p1];
        const int t2 = (c2 * ROWS + 2 * (p2i / 7)) * SROW + s_dx[p2i];

        f4 va[4], vb[4];

#define STAGE(vv, g)                                                          \
        {                                                                     \
            const float* fg = fbase + (size_t)((g) * CG) * HW;                \
            _Pragma("unroll")                                                 \
            for (int pp = 0; pp < 4; ++pp)                                    \
                if (gact[pp]) vv[pp] = *(const f4*)(fg + goff[pp]);           \
        }
#define LDSWRITE(buf, vv)                                                     \
        {                                                                     \
            _Pragma("unroll")                                                 \
            for (int pp = 0; pp < 4; ++pp)                                    \
                if (gact[pp]) *(f4*)(&s_stage[buf][lw[pp]]) = vv[pp];         \
        }
#define COMPUTE(g, buf)                                                       \
        {                                                                     \
            const float* st = s_stage[buf];                                   \
            const float t00 = st[t1],        t01 = st[t1 + 1];                \
            const float t10 = st[t1 + SROW], t11 = st[t1 + SROW + 1];         \
            op[(g) * GROUP_OUT + tid] =                                       \
                (t00 * a1 + t01 * b1) * w01 + (t10 * a1 + t11 * b1) * w11;    \
            if (act2) {                                                       \
                const float u00 = st[t2],        u01 = st[t2 + 1];            \
                const float u10 = st[t2 + SROW], u11 = st[t2 + SROW + 1];     \
                op[(g) * GROUP_OUT + 256 + tid] =                             \
                    (u00 * a2 + u01 * b2) * w02 + (u10 * a2 + u11 * b2) * w12;\
            }                                                                 \
        }

        STAGE(va, 0);
#pragma unroll
        for (int g = 0; g < NGROUPS; g += 2) {
            // iter even: buffer 0 holds group g
            LDSWRITE(0, va);                 // waits vmcnt on va internally
            STAGE(vb, g + 1);                // next group's loads in flight
            __syncthreads();
            COMPUTE(g, 0);
            // iter odd: buffer 1 holds group g+1
            LDSWRITE(1, vb);
            if (g + 2 < NGROUPS) STAGE(va, g + 2);
            __syncthreads();
            COMPUTE(g + 1, 1);
        }
#undef STAGE
#undef LDSWRITE
#undef COMPUTE
    } else {
        // wide-window fallback: proven R3-style float2 gathers, same output map
        const int off01 = s_off0[p1],  off11 = s_off1[p1];
        const int off02 = s_off0[p2i], off12 = s_off1[p2i];
        for (int g = 0; g < NGROUPS; ++g) {
            const float* pl1 = fbase + (size_t)(g * CG + c1) * HW;
            const f2 q0 = *(const f2*)(pl1 + off01);
            const f2 q1 = *(const f2*)(pl1 + off11);
            const float r0 = q0.x * a1 + q0.y * b1;
            const float r1 = q1.x * a1 + q1.y * b1;
            op[g * GROUP_OUT + tid] = r0 * w01 + r1 * w11;
            if (act2) {
                const float* pl2 = fbase + (size_t)(g * CG + c2) * HW;
                const f2 u0 = *(const f2*)(pl2 + off02);
                const f2 u1 = *(const f2*)(pl2 + off12);
                const float s0 = u0.x * a2 + u0.y * b2;
                const float s1 = u1.x * a2 + u1.y * b2;
                op[g * GROUP_OUT + 256 + tid] = s0 * w02 + s1 * w12;
            }
        }
    }
}

extern "C" void kernel_launch(void* const* d_in, const int* in_sizes, int n_in,
                              void* d_out, int out_size, void* d_ws, size_t ws_size,
                              hipStream_t stream) {
    const float* boxes = (const float*)d_in[0];
    const float* p2    = (const float*)d_in[1];
    const float* p3    = (const float*)d_in[2];
    const float* p4    = (const float*)d_in[3];
    const float* p5    = (const float*)d_in[4];
    float* out = (float*)d_out;
    const int N = in_sizes[0] / 4;

    roi_align_kernel<<<N * 4, 256, 0, stream>>>(boxes, p2, p3, p4, p5, out, N);
}

// Round 4
// 149.251 us; speedup vs baseline: 1.4350x; 1.4350x over previous
//
#include <hip/hip_runtime.h>

// pyramid_roi_align (Mask R-CNN), MI355X.
// R6: R5b's register-prefetch arrays spilled to scratch (+113MB HBM writes,
// VGPR/SGPR 64/112) and the barrier drained the "prefetch" anyway. R6 stages
// via global_load_lds width=16 (no VGPR round trip, no scratch): compact
// lane-linear LDS layout, row stride s4 float4s rounded to ODD (bank
// rotation), untapped overflow slots clamped to level end. True depth-1
// pipeline: barrier -> issue g+1 (async) -> compute g; one barrier/group,
// loads fly under compute, drained at the next barrier. 4 blocks/box.
// Wide-x-window boxes (need > 32 cols) keep the proven R3 gather fallback
// (y-extent never forces fallback: the 14 rows are staged individually).

#define POOL 7
#define NCH  256
#define ELEMS_PER_BOX (NCH * POOL * POOL)    // 12544
#define QCH 64                               // channels per block
#define QELEMS (QCH * POOL * POOL)           // 3136
#define CG 8                                 // channels per staging group
#define NGROUPS (QCH / CG)                   // 8
#define ROWS 14                              // 2 rows (y0,y1) per py
#define MAXS4 9                              // max (odd-padded) float4s/row
#define BUFSLOTS (CG * ROWS * MAXS4)         // 1008 float4 slots = 16128 B
#define GROUP_OUT (CG * 49)                  // 392 outputs per group

typedef float f2 __attribute__((ext_vector_type(2)));
typedef __attribute__((address_space(1))) const void* gas_ptr;
typedef __attribute__((address_space(3))) void*       las_ptr;

__global__ __launch_bounds__(256, 4) void roi_align_kernel(
    const float* __restrict__ boxes,
    const float* __restrict__ p2, const float* __restrict__ p3,
    const float* __restrict__ p4, const float* __restrict__ p5,
    float* __restrict__ out, int N)
{
    const int bid     = blockIdx.x;
    const int n       = bid >> 2;   // box
    const int quarter = bid & 3;    // channel quarter: [64q, 64q+64)

    __shared__ float s_stage[2][BUFSLOTS * 4];    // 2 x 16128 B
    __shared__ float s_a[49], s_b[49], s_w0[49], s_w1[49];
    __shared__ int   s_dx[49];                    // xb - xb0 (float idx in window)
    __shared__ int   s_off0[49], s_off1[49];      // fallback gather offsets
    __shared__ int   s_rowoff[ROWS];              // y*W for the 14 rows
    __shared__ int   s_HW, s_xb0, s_s4, s_fast;
    __shared__ const float* s_fmap;

    const int tid = threadIdx.x;

    if (tid < 49) {
        const float by1 = boxes[4 * n + 0];
        const float bx1 = boxes[4 * n + 1];
        const float by2 = boxes[4 * n + 2];
        const float bx2 = boxes[4 * n + 3];
        const float h = by2 - by1;
        const float w = bx2 - bx1;
        float rl = 4.0f + log2f(sqrtf(h * w) / 0.21875f);
        int level = (int)rintf(rl);            // round-half-even = jnp.round
        level = min(5, max(2, level));
        const int H = 256 >> (level - 2);
        const int W = H;
        const int py = tid / 7;
        const int px = tid - 7 * py;

        // y interp
        const float ty = (float)py / 6.0f;
        const float ys = (by1 + ty * (by2 - by1)) * (float)(H - 1);
        const float yf = floorf(ys);
        const float ly = ys - yf;
        int y0 = (int)yf; y0 = min(H - 1, max(0, y0));
        const int y1 = min(H - 1, y0 + 1);
        const float vy = (ys >= 0.0f && ys <= (float)(H - 1)) ? 1.0f : 0.0f;

        // x interp
        const float tx = (float)px / 6.0f;
        const float xs = (bx1 + tx * (bx2 - bx1)) * (float)(W - 1);
        const float xf = floorf(xs);
        const float lx = xs - xf;
        int x0 = (int)xf; x0 = min(W - 1, max(0, x0));
        const float vx = (xs >= 0.0f && xs <= (float)(W - 1)) ? 1.0f : 0.0f;
        const int xb = min(x0, W - 2);         // float2 base column
        const bool edge = (x0 != xb);
        const float a = edge ? 0.0f : vx * (1.0f - lx);
        const float b = edge ? vx : vx * lx;

        // x window endpoints, recomputed identically by every thread (tx=0,1)
        const float xsA = bx1 * (float)(W - 1);
        int xA = (int)floorf(xsA); xA = min(W - 1, max(0, xA));
        const int xbA = min(xA, W - 2);
        const float xsB = bx2 * (float)(W - 1);
        int xB = (int)floorf(xsB); xB = min(W - 1, max(0, xB));
        const int xbB = min(xB, W - 2);
        const int xb0  = xbA & ~3;                // 16B-aligned window start
        const int need = xbB + 2 - xb0;           // cols needed from xb0
        const int sa4  = (need + 3) >> 2;         // float4s/row (1..8 if fast)

        s_off0[tid] = y0 * W + xb;
        s_off1[tid] = y1 * W + xb;
        s_a[tid] = a;
        s_b[tid] = b;
        s_w0[tid] = vy * (1.0f - ly);
        s_w1[tid] = vy * ly;
        s_dx[tid] = xb - xb0;
        if (px == 0) {
            s_rowoff[2 * py]     = y0 * W;
            s_rowoff[2 * py + 1] = y1 * W;
        }
        if (tid == 0) {
            s_HW   = H * W;
            s_fmap = (level == 2) ? p2 : (level == 3) ? p3 : (level == 4) ? p4 : p5;
            s_xb0  = xb0;
            s_s4   = sa4 | 1;                     // odd stride: bank rotation
            s_fast = (need <= 32) ? 1 : 0;
        }
    }
    __syncthreads();

    const int HW = s_HW;
    const float* __restrict__ lvl = s_fmap;
    float* __restrict__ op = out + (size_t)n * ELEMS_PER_BOX + quarter * QELEMS;

    // two output slots per thread per group (392 = 256 + 136)
    const int c1  = tid / 49,  p1  = tid - 49 * c1;
    const int o2  = 256 + tid;
    const int c2  = o2 / 49,   p2i = o2 - 49 * c2;
    const bool act2 = (tid < GROUP_OUT - 256);

    const float a1 = s_a[p1],  b1 = s_b[p1],  w01 = s_w0[p1],  w11 = s_w1[p1];
    const float a2 = s_a[p2i], b2 = s_b[p2i], w02 = s_w0[p2i], w12 = s_w1[p2i];

    if (s_fast) {
        const int s4 = s_s4;                  // odd, 1..9
        const int S  = 4 * s4;                // LDS row stride in floats
        const int nslots = CG * ROWS * s4;    // 112*s4 <= 1008
        const unsigned lim = (unsigned)(NCH * HW - 4);
        const unsigned cb  = (unsigned)(quarter * QCH) * (unsigned)HW;
        const int xb0 = s_xb0;

        // per-slot channel-relative base offsets (named scalars: no arrays)
        unsigned g0 = 0, g1 = 0, g2v = 0, g3 = 0;
#define SLOTMETA(bvar, k)                                                     \
        { const int idx = (k)*256 + tid;                                      \
          if (idx < nslots) {                                                 \
              const int rid = idx / s4;                                       \
              const int q   = idx - rid * s4;                                 \
              const int cl  = rid / 14;                                       \
              const int r   = rid - 14 * cl;                                  \
              bvar = cb + (unsigned)(cl * HW + s_rowoff[r] + xb0 + 4 * q);    \
          } }
        SLOTMETA(g0, 0) SLOTMETA(g1, 1) SLOTMETA(g2v, 2) SLOTMETA(g3, 3)
#undef SLOTMETA

        // per-thread tap bases (floats into a stage buffer)
        const int t1 = (c1 * ROWS + 2 * (p1 / 7)) * S + s_dx[p1];
        const int t2 = (c2 * ROWS + 2 * (p2i / 7)) * S + s_dx[p2i];

#define GLD(bvar, k, gs, sb)                                                  \
        { const int idx = (k)*256 + tid;                                      \
          if (idx < nslots) {                                                 \
              const unsigned o = min(bvar + (gs), lim);                       \
              __builtin_amdgcn_global_load_lds((gas_ptr)(lvl + o),            \
                  (las_ptr)((sb) + idx * 4), 16, 0, 0);                       \
          } }
#define ISSUE(g, bi)                                                          \
        { const unsigned gs = (unsigned)((g) * CG * HW);                      \
          float* sb = s_stage[bi];                                            \
          GLD(g0, 0, gs, sb) GLD(g1, 1, gs, sb)                               \
          GLD(g2v, 2, gs, sb) GLD(g3, 3, gs, sb) }
#define COMPUTE(g, bi)                                                        \
        { const float* st = s_stage[bi];                                      \
          { const float t00 = st[t1],     t01 = st[t1 + 1];                   \
            const float t10 = st[t1 + S], t11 = st[t1 + S + 1];               \
            op[(g) * GROUP_OUT + tid] =                                       \
                (t00 * a1 + t01 * b1) * w01 + (t10 * a1 + t11 * b1) * w11; }  \
          if (act2) {                                                         \
            const float u00 = st[t2],     u01 = st[t2 + 1];                   \
            const float u10 = st[t2 + S], u11 = st[t2 + S + 1];               \
            op[(g) * GROUP_OUT + 256 + tid] =                                 \
                (u00 * a2 + u01 * b2) * w02 + (u10 * a2 + u11 * b2) * w12; } }

        ISSUE(0, 0);
#pragma unroll
        for (int g = 0; g < NGROUPS; ++g) {
            __syncthreads();                    // drains vmcnt -> buf[g&1] ready
            if (g + 1 < NGROUPS) ISSUE(g + 1, (g + 1) & 1);  // flies under compute
            COMPUTE(g, g & 1);
        }
#undef GLD
#undef ISSUE
#undef COMPUTE
    } else {
        // wide-x-window fallback: proven R3-style float2 gathers, same output map
        const int off01 = s_off0[p1],  off11 = s_off1[p1];
        const int off02 = s_off0[p2i], off12 = s_off1[p2i];
        const float* __restrict__ fbase = lvl + (size_t)(quarter * QCH) * HW;
        for (int g = 0; g < NGROUPS; ++g) {
            const float* pl1 = fbase + (size_t)(g * CG + c1) * HW;
            const f2 q0 = *(const f2*)(pl1 + off01);
            const f2 q1 = *(const f2*)(pl1 + off11);
            const float r0 = q0.x * a1 + q0.y * b1;
            const float r1 = q1.x * a1 + q1.y * b1;
            op[g * GROUP_OUT + tid] = r0 * w01 + r1 * w11;
            if (act2) {
                const float* pl2 = fbase + (size_t)(g * CG + c2) * HW;
                const f2 u0 = *(const f2*)(pl2 + off02);
                const f2 u1 = *(const f2*)(pl2 + off12);
                const float s0 = u0.x * a2 + u0.y * b2;
                const float s1 = u1.x * a2 + u1.y * b2;
                op[g * GROUP_OUT + 256 + tid] = s0 * w02 + s1 * w12;
            }
        }
    }
}

extern "C" void kernel_launch(void* const* d_in, const int* in_sizes, int n_in,
                              void* d_out, int out_size, void* d_ws, size_t ws_size,
                              hipStream_t stream) {
    const float* boxes = (const float*)d_in[0];
    const float* p2    = (const float*)d_in[1];
    const float* p3    = (const float*)d_in[2];
    const float* p4    = (const float*)d_in[3];
    const float* p5    = (const float*)d_in[4];
    float* out = (float*)d_out;
    const int N = in_sizes[0] / 4;

    roi_align_kernel<<<N * 4, 256, 0, stream>>>(boxes, p2, p3, p4, p5, out, N);
}

// Round 6
// 147.616 us; speedup vs baseline: 1.4509x; 1.0111x over previous
//
#include <hip/hip_runtime.h>

// pyramid_roi_align (Mask R-CNN), MI355X.
// R7b: verbatim resubmit of R7 (round 5 died at container acquire twice --
// same infra signature as round 2, whose resubmit then ran fine; audit found
// no fault/hang path in-kernel: no loop barriers, all global addrs clamped,
// LDS/tap/store indices proven in-bounds).
// Design: R6 proved staging cuts TA line-visits 3.5x (FETCH 30MB, WRITE 49MB,
// no scratch) but its 8 barrier-drains/block serialized everything (occ 27%,
// VALU 21% -> 48us). R7 removes ALL main-loop barriers: each wave stages its
// OWN 16 channels into its OWN LDS slice (4 steps x 4ch), waits its own vmcnt
// (wave-local, no block sync), computes, stores. 16 waves/CU hide each
// other's drains. Metadata precomputed once into named scalars (no arrays ->
// no scratch). Wide-window boxes (~10%) keep the proven gather fallback.

#define POOL 7
#define NCH  256
#define ELEMS_PER_BOX (NCH * POOL * POOL)    // 12544
#define QCH 64                               // channels per block
#define WCH 16                               // channels per wave
#define SCH 4                                // channels per step
#define NSTEPS 4                             // WCH / SCH
#define ROWS 14                              // 2 rows (y0,y1) per py
#define SLOTS 512                            // f4 slots per wave slice (8 GLD x 64)
#define CG 8                                 // fallback: channels per group
#define NGROUPS 8                            // fallback groups
#define GROUP_OUT (CG * 49)                  // 392

typedef float f2 __attribute__((ext_vector_type(2)));
typedef __attribute__((address_space(1))) const void* gas_ptr;
typedef __attribute__((address_space(3))) void*       las_ptr;

__global__ __launch_bounds__(256, 4) void roi_align_kernel(
    const float* __restrict__ boxes,
    const float* __restrict__ p2, const float* __restrict__ p3,
    const float* __restrict__ p4, const float* __restrict__ p5,
    float* __restrict__ out, int N)
{
    const int bid     = blockIdx.x;
    const int n       = bid >> 2;   // box
    const int quarter = bid & 3;    // channel quarter [64q, 64q+64)

    __shared__ float s_stage[4][SLOTS * 4];       // 32 KB: one slice per wave
    __shared__ float s_a[49], s_b[49], s_w0[49], s_w1[49];
    __shared__ int   s_dx[49];                    // xb - xb0
    __shared__ int   s_off0[49], s_off1[49];      // fallback gather offsets
    __shared__ int   s_rowoff[ROWS];              // y*W for the 14 rows
    __shared__ int   s_HW, s_xb0, s_s4s, s_fast;
    __shared__ const float* s_fmap;

    const int tid = threadIdx.x;

    if (tid < 49) {
        const float by1 = boxes[4 * n + 0];
        const float bx1 = boxes[4 * n + 1];
        const float by2 = boxes[4 * n + 2];
        const float bx2 = boxes[4 * n + 3];
        const float h = by2 - by1;
        const float w = bx2 - bx1;
        float rl = 4.0f + log2f(sqrtf(h * w) / 0.21875f);
        int level = (int)rintf(rl);            // round-half-even = jnp.round
        level = min(5, max(2, level));
        const int H = 256 >> (level - 2);
        const int W = H;
        const int py = tid / 7;
        const int px = tid - 7 * py;

        // y interp
        const float ty = (float)py / 6.0f;
        const float ys = (by1 + ty * (by2 - by1)) * (float)(H - 1);
        const float yf = floorf(ys);
        const float ly = ys - yf;
        int y0 = (int)yf; y0 = min(H - 1, max(0, y0));
        const int y1 = min(H - 1, y0 + 1);
        const float vy = (ys >= 0.0f && ys <= (float)(H - 1)) ? 1.0f : 0.0f;

        // x interp
        const float tx = (float)px / 6.0f;
        const float xs = (bx1 + tx * (bx2 - bx1)) * (float)(W - 1);
        const float xf = floorf(xs);
        const float lx = xs - xf;
        int x0 = (int)xf; x0 = min(W - 1, max(0, x0));
        const float vx = (xs >= 0.0f && xs <= (float)(W - 1)) ? 1.0f : 0.0f;
        const int xb = min(x0, W - 2);         // float2 base column
        const bool edge = (x0 != xb);
        const float a = edge ? 0.0f : vx * (1.0f - lx);
        const float b = edge ? vx : vx * lx;

        // x window endpoints, recomputed identically by every thread (tx=0,1)
        const float xsA = bx1 * (float)(W - 1);
        int xA = (int)floorf(xsA); xA = min(W - 1, max(0, xA));
        const int xbA = min(xA, W - 2);
        const float xsB = bx2 * (float)(W - 1);
        int xB = (int)floorf(xsB); xB = min(W - 1, max(0, xB));
        const int xbB = min(xB, W - 2);
        const int xb0  = xbA & ~3;                // 16B-aligned window start
        const int need = xbB + 2 - xb0;           // cols needed from xb0
        const int sa4  = (need + 3) >> 2;         // float4s/row (1..8 if fast)

        s_off0[tid] = y0 * W + xb;
        s_off1[tid] = y1 * W + xb;
        s_a[tid] = a;
        s_b[tid] = b;
        s_w0[tid] = vy * (1.0f - ly);
        s_w1[tid] = vy * ly;
        s_dx[tid] = xb - xb0;
        if (px == 0) {
            s_rowoff[2 * py]     = y0 * W;
            s_rowoff[2 * py + 1] = y1 * W;
        }
        if (tid == 0) {
            s_HW   = H * W;
            s_fmap = (level == 2) ? p2 : (level == 3) ? p3 : (level == 4) ? p4 : p5;
            s_xb0  = xb0;
            s_s4s  = sa4 | 1;                     // odd stride: bank rotation
            s_fast = (need <= 32) ? 1 : 0;
        }
    }
    __syncthreads();                 // the ONLY block-wide barrier

    const int HW = s_HW;
    const float* __restrict__ lvl = s_fmap;
    const int lane = tid & 63;
    const int wave = tid >> 6;

    if (s_fast) {
        const int s4s = s_s4s;                  // odd, 1..9
        const int S   = 4 * s4s;                // LDS row stride (floats)
        const int nslots = 56 * s4s;            // live f4 slots per step (<=504)
        const unsigned lim = (unsigned)(NCH * HW - 4);
        float* const slice = s_stage[wave];
        const int chbase = quarter * QCH + wave * WCH;
        const unsigned cb0 = (unsigned)chbase * (unsigned)HW;

        // per-GLD slot metadata: channel-relative float offsets (named scalars)
        unsigned inv0, inv1, inv2, inv3, inv4, inv5, inv6, inv7;
#define SLOTMETA(k, bvar)                                                     \
        { const int idx = (k) * 64 + lane;                                    \
          if (idx < nslots) {                                                 \
              const int rid = idx / s4s;            /* ch-row slot 0..55 */   \
              const int q   = idx - rid * s4s;      /* float4 within row */   \
              const int cl  = rid / 14;             /* channel 0..3      */   \
              const int r   = rid - 14 * cl;        /* row slot 0..13    */   \
              bvar = (unsigned)(cl * HW + s_rowoff[r] + s_xb0 + 4 * q);       \
          } else bvar = 0x40000000u; }              /* sentinel -> clamps */
        SLOTMETA(0, inv0) SLOTMETA(1, inv1) SLOTMETA(2, inv2) SLOTMETA(3, inv3)
        SLOTMETA(4, inv4) SLOTMETA(5, inv5) SLOTMETA(6, inv6) SLOTMETA(7, inv7)
#undef SLOTMETA

        // per-pass cell metadata (named scalars, constant across steps)
        bool  act0, act1, act2_, act3;
        int   to0, to1, to2, to3;
        float aa0, bb0, w00, w10, aa1, bb1, w01, w11;
        float aa2, bb2, w02, w12, aa3, bb3, w03, w13;
#define CELLMETA(j, act, to, aa, bb, w0v, w1v)                                \
        { const int oidx = (j) * 64 + lane;                                   \
          act = (oidx < SCH * 49);                                            \
          const int oc = min(oidx, SCH * 49 - 1);                             \
          const int cc = oc / 49;                                             \
          const int pp = oc - 49 * cc;                                        \
          to  = (cc * ROWS + 2 * (pp / 7)) * S + s_dx[pp];                    \
          aa = s_a[pp]; bb = s_b[pp]; w0v = s_w0[pp]; w1v = s_w1[pp]; }
        CELLMETA(0, act0, to0, aa0, bb0, w00, w10)
        CELLMETA(1, act1, to1, aa1, bb1, w01, w11)
        CELLMETA(2, act2_, to2, aa2, bb2, w02, w12)
        CELLMETA(3, act3, to3, aa3, bb3, w03, w13)
#undef CELLMETA

        float* __restrict__ opw =
            out + (size_t)n * ELEMS_PER_BOX + (size_t)chbase * 49;

        for (int s = 0; s < NSTEPS; ++s) {
            const unsigned stepoff = cb0 + (unsigned)(s * SCH * HW);
            // issue this step's loads (wave-private slice, no sync needed)
#define GLD(k, bvar)                                                          \
            if ((k) * 64 < nslots) {                                          \
                const unsigned o = min(stepoff + bvar, lim);                  \
                __builtin_amdgcn_global_load_lds((gas_ptr)(lvl + o),          \
                    (las_ptr)(slice + ((k) * 64 + lane) * 4), 16, 0, 0);      \
            }
            GLD(0, inv0) GLD(1, inv1) GLD(2, inv2) GLD(3, inv3)
            GLD(4, inv4) GLD(5, inv5) GLD(6, inv6) GLD(7, inv7)
#undef GLD
            // wave-local drain; other waves on the SIMD run during this
            asm volatile("s_waitcnt vmcnt(0)" ::: "memory");
            __builtin_amdgcn_sched_barrier(0);   // rule #18: pin ds_reads below

            float* __restrict__ o_s = opw + s * (SCH * 49);
#define CELL(j, act, to, aa, bb, w0v, w1v)                                    \
            if (act) {                                                        \
                const float t00 = slice[(to)],     t01 = slice[(to) + 1];     \
                const float t10 = slice[(to) + S], t11 = slice[(to) + S + 1]; \
                o_s[(j) * 64 + lane] =                                        \
                    (t00 * aa + t01 * bb) * w0v + (t10 * aa + t11 * bb) * w1v;\
            }
            CELL(0, act0, to0, aa0, bb0, w00, w10)
            CELL(1, act1, to1, aa1, bb1, w01, w11)
            CELL(2, act2_, to2, aa2, bb2, w02, w12)
            CELL(3, act3, to3, aa3, bb3, w03, w13)
#undef CELL
            // keep next iter's GLDs (LDS writes) below this iter's LDS reads
            __builtin_amdgcn_sched_barrier(0);
            asm volatile("" ::: "memory");
        }
    } else {
        // wide-x-window fallback: proven R3-style float2 gathers (no barriers)
        const int c1  = tid / 49,  p1  = tid - 49 * c1;
        const int o2  = 256 + tid;
        const int c2  = o2 / 49,   p2i = o2 - 49 * c2;
        const bool act2 = (tid < GROUP_OUT - 256);

        const float a1 = s_a[p1],  b1 = s_b[p1],  w01f = s_w0[p1],  w11f = s_w1[p1];
        const float a2 = s_a[p2i], b2 = s_b[p2i], w02f = s_w0[p2i], w12f = s_w1[p2i];
        const int off01 = s_off0[p1],  off11 = s_off1[p1];
        const int off02 = s_off0[p2i], off12 = s_off1[p2i];

        const float* __restrict__ fbase = lvl + (size_t)(quarter * QCH) * HW;
        float* __restrict__ op =
            out + (size_t)n * ELEMS_PER_BOX + quarter * (QCH * 49);
        for (int g = 0; g < NGROUPS; ++g) {
            const float* pl1 = fbase + (size_t)(g * CG + c1) * HW;
            const f2 q0 = *(const f2*)(pl1 + off01);
            const f2 q1 = *(const f2*)(pl1 + off11);
            const float r0 = q0.x * a1 + q0.y * b1;
            const float r1 = q1.x * a1 + q1.y * b1;
            op[g * GROUP_OUT + tid] = r0 * w01f + r1 * w11f;
            if (act2) {
                const float* pl2 = fbase + (size_t)(g * CG + c2) * HW;
                const f2 u0 = *(const f2*)(pl2 + off02);
                const f2 u1 = *(const f2*)(pl2 + off12);
                const float s0 = u0.x * a2 + u0.y * b2;
                const float s1 = u1.x * a2 + u1.y * b2;
                op[g * GROUP_OUT + 256 + tid] = s0 * w02f + s1 * w12f;
            }
        }
    }
}

extern "C" void kernel_launch(void* const* d_in, const int* in_sizes, int n_in,
                              void* d_out, int out_size, void* d_ws, size_t ws_size,
                              hipStream_t stream) {
    const float* boxes = (const float*)d_in[0];
    const float* p2    = (const float*)d_in[1];
    const float* p3    = (const float*)d_in[2];
    const float* p4    = (const float*)d_in[3];
    const float* p5    = (const float*)d_in[4];
    float* out = (float*)d_out;
    const int N = in_sizes[0] / 4;

    roi_align_kernel<<<N * 4, 256, 0, stream>>>(boxes, p2, p3, p4, p5, out, N);
}

// Round 7
// 145.096 us; speedup vs baseline: 1.4761x; 1.0174x over previous
//
#include <hip/hip_runtime.h>

// pyramid_roi_align (Mask R-CNN), MI355X.
// R8: R6 (8 barrier-drains) and R7 (zero barriers, per-step vmcnt(0)) tied at
// 48us -> the bottleneck is exposed load latency (issue-to-wait distance ~0
// every step), not barriers. R8 builds the real pipeline: per-wave double-
// buffered slices, COUNTED vmcnt(G) waits (next batch stays in flight across
// the compute), batch size G made compile-time by templating on s4s (also
// kills runtime divisions), outputs accumulated in 16 named registers and
// stored once (stores out of the vmcnt chain). 128-thr blocks, 8000 blocks,
// ~30KB LDS -> 5 blocks/CU. Wide boxes (need>28) keep the gather fallback.

#define POOL 7
#define NCH  256
#define ELEMS_PER_BOX (NCH * POOL * POOL)    // 12544
#define ECH 32                               // channels per block
#define WCH 16                               // channels per wave
#define SCH 4                                // channels per batch/step
#define NSTEPS 4
#define ROWS 14                              // 2 rows (y0,y1) per py
#define MAXG 7                               // max GLD instrs per batch
#define BUFSLOT (MAXG * 64)                  // 448 f4 slots per buffer (7168 B)
#define STEPOUT (SCH * 49)                   // 196 outputs per step

typedef float f2 __attribute__((ext_vector_type(2)));
typedef __attribute__((address_space(1))) const void* gas_ptr;
typedef __attribute__((address_space(3))) void*       las_ptr;

#define VMWAIT(n) asm volatile("s_waitcnt vmcnt(" #n ")" ::: "memory")

template<int S4S>
__device__ __forceinline__ void fast_steps(
    const float* __restrict__ lvl, float* __restrict__ opw,
    float* __restrict__ buf0, float* __restrict__ buf1,
    const int lane, const int HW, const unsigned cb0, const unsigned lim,
    const int xb0, const int* s_rowoff, const int* s_dx,
    const float* s_a, const float* s_b, const float* s_w0, const float* s_w1)
{
    constexpr int G   = (56 * S4S + 63) / 64;   // GLDs per batch: 1,3,5,7
    constexpr int S   = 4 * S4S;                // LDS row stride (floats)
    constexpr int NSL = 56 * S4S;               // live f4 slots per batch

    // ---- slot metadata (channel-relative float offsets), named scalars ----
    unsigned inv0 = 0x40000000u, inv1 = 0x40000000u, inv2 = 0x40000000u,
             inv3 = 0x40000000u, inv4 = 0x40000000u, inv5 = 0x40000000u,
             inv6 = 0x40000000u;
#define SLOTMETA(k, var)                                                      \
    if constexpr ((k) < G) {                                                  \
        const int idx = (k) * 64 + lane;                                      \
        if (idx < NSL) {                                                      \
            const int rid = idx / S4S;          /* const div */               \
            const int q   = idx - rid * S4S;                                  \
            const int cl  = rid / 14;                                         \
            const int r   = rid - 14 * cl;                                    \
            var = (unsigned)(cl * HW + s_rowoff[r] + xb0 + 4 * q);            \
        }                                                                     \
    }
    SLOTMETA(0, inv0) SLOTMETA(1, inv1) SLOTMETA(2, inv2) SLOTMETA(3, inv3)
    SLOTMETA(4, inv4) SLOTMETA(5, inv5) SLOTMETA(6, inv6)
#undef SLOTMETA

    // ---- cell metadata (4 output slots/step), named scalars ----
    int   to0, to1, to2, to3;
    float aa0, bb0, w00, w10, aa1, bb1, w01, w11;
    float aa2, bb2, w02, w12, aa3, bb3, w03, w13;
#define CELLMETA(j, tov, aav, bbv, w0v, w1v)                                  \
    { int oidx = (j) * 64 + lane;                                             \
      oidx = oidx < STEPOUT ? oidx : STEPOUT - 1;                             \
      const int cc = oidx / 49;                                               \
      const int pp = oidx - 49 * cc;                                          \
      tov = (cc * ROWS + 2 * (pp / 7)) * S + s_dx[pp];                        \
      aav = s_a[pp]; bbv = s_b[pp]; w0v = s_w0[pp]; w1v = s_w1[pp]; }
    CELLMETA(0, to0, aa0, bb0, w00, w10)
    CELLMETA(1, to1, aa1, bb1, w01, w11)
    CELLMETA(2, to2, aa2, bb2, w02, w12)
    CELLMETA(3, to3, aa3, bb3, w03, w13)
#undef CELLMETA

#define GLD1(k, var, so, bp)                                                  \
    if constexpr ((k) < G) {                                                  \
        unsigned o_ = (so) + var; o_ = o_ > lim ? lim : o_;                   \
        __builtin_amdgcn_global_load_lds((gas_ptr)(lvl + o_),                 \
            (las_ptr)((bp) + ((k) * 64 + lane) * 4), 16, 0, 0);               \
    }
#define ISSUE(t, bp)                                                          \
    { const unsigned so_ = cb0 + (unsigned)((t) * SCH * HW);                  \
      GLD1(0, inv0, so_, bp) GLD1(1, inv1, so_, bp) GLD1(2, inv2, so_, bp)    \
      GLD1(3, inv3, so_, bp) GLD1(4, inv4, so_, bp) GLD1(5, inv5, so_, bp)    \
      GLD1(6, inv6, so_, bp) }
#define CELLC(bp, tov, aav, bbv, w0v, w1v, rvar)                              \
    { const float t00 = (bp)[tov],     t01 = (bp)[tov + 1];                   \
      const float t10 = (bp)[tov + S], t11 = (bp)[tov + S + 1];               \
      rvar = (t00 * aav + t01 * bbv) * w0v + (t10 * aav + t11 * bbv) * w1v; }
#define VMWAIT_G                                                              \
    if constexpr (G == 1) { VMWAIT(1); }                                      \
    else if constexpr (G == 3) { VMWAIT(3); }                                 \
    else if constexpr (G == 5) { VMWAIT(5); }                                 \
    else { VMWAIT(7); }

    float r00, r01, r02, r03, r10, r11, r12, r13;
    float r20, r21, r22, r23, r30, r31, r32, r33;

    // prologue: two batches in flight
    ISSUE(0, buf0)
    ISSUE(1, buf1)

    // step 0: wait b0 (b1 stays in flight), compute, refill buf0 with b2
    VMWAIT_G;
    __builtin_amdgcn_sched_barrier(0);
    CELLC(buf0, to0, aa0, bb0, w00, w10, r00)
    CELLC(buf0, to1, aa1, bb1, w01, w11, r01)
    CELLC(buf0, to2, aa2, bb2, w02, w12, r02)
    CELLC(buf0, to3, aa3, bb3, w03, w13, r03)
    asm volatile("s_waitcnt lgkmcnt(0)" ::: "memory");   // reads retired
    __builtin_amdgcn_sched_barrier(0);
    ISSUE(2, buf0)

    // step 1
    VMWAIT_G;
    __builtin_amdgcn_sched_barrier(0);
    CELLC(buf1, to0, aa0, bb0, w00, w10, r10)
    CELLC(buf1, to1, aa1, bb1, w01, w11, r11)
    CELLC(buf1, to2, aa2, bb2, w02, w12, r12)
    CELLC(buf1, to3, aa3, bb3, w03, w13, r13)
    asm volatile("s_waitcnt lgkmcnt(0)" ::: "memory");
    __builtin_amdgcn_sched_barrier(0);
    ISSUE(3, buf1)

    // step 2 (b3 stays in flight)
    VMWAIT_G;
    __builtin_amdgcn_sched_barrier(0);
    CELLC(buf0, to0, aa0, bb0, w00, w10, r20)
    CELLC(buf0, to1, aa1, bb1, w01, w11, r21)
    CELLC(buf0, to2, aa2, bb2, w02, w12, r22)
    CELLC(buf0, to3, aa3, bb3, w03, w13, r23)

    // step 3: final drain
    VMWAIT(0);
    __builtin_amdgcn_sched_barrier(0);
    CELLC(buf1, to0, aa0, bb0, w00, w10, r30)
    CELLC(buf1, to1, aa1, bb1, w01, w11, r31)
    CELLC(buf1, to2, aa2, bb2, w02, w12, r32)
    CELLC(buf1, to3, aa3, bb3, w03, w13, r33)

    // epilogue: coalesced stores (196 outputs/step = 3*64 + 4)
    const bool tail = (lane < STEPOUT - 192);
    opw[0 * STEPOUT +   0 + lane] = r00;
    opw[0 * STEPOUT +  64 + lane] = r01;
    opw[0 * STEPOUT + 128 + lane] = r02;
    if (tail) opw[0 * STEPOUT + 192 + lane] = r03;
    opw[1 * STEPOUT +   0 + lane] = r10;
    opw[1 * STEPOUT +  64 + lane] = r11;
    opw[1 * STEPOUT + 128 + lane] = r12;
    if (tail) opw[1 * STEPOUT + 192 + lane] = r13;
    opw[2 * STEPOUT +   0 + lane] = r20;
    opw[2 * STEPOUT +  64 + lane] = r21;
    opw[2 * STEPOUT + 128 + lane] = r22;
    if (tail) opw[2 * STEPOUT + 192 + lane] = r23;
    opw[3 * STEPOUT +   0 + lane] = r30;
    opw[3 * STEPOUT +  64 + lane] = r31;
    opw[3 * STEPOUT + 128 + lane] = r32;
    if (tail) opw[3 * STEPOUT + 192 + lane] = r33;

#undef GLD1
#undef ISSUE
#undef CELLC
#undef VMWAIT_G
}

__global__ __launch_bounds__(128, 4) void roi_align_kernel(
    const float* __restrict__ boxes,
    const float* __restrict__ p2, const float* __restrict__ p3,
    const float* __restrict__ p4, const float* __restrict__ p5,
    float* __restrict__ out, int N)
{
    const int bid    = blockIdx.x;
    const int n      = bid >> 3;    // box
    const int eighth = bid & 7;     // channel 32-block [32e, 32e+32)

    __shared__ float s_stage[2][2][BUFSLOT * 4];  // 28672 B: wave x dbuf
    __shared__ float s_a[49], s_b[49], s_w0[49], s_w1[49];
    __shared__ int   s_dx[49];
    __shared__ int   s_off0[49], s_off1[49];      // fallback gather offsets
    __shared__ int   s_rowoff[ROWS];
    __shared__ int   s_HW, s_xb0, s_sel;
    __shared__ const float* s_fmap;

    const int tid = threadIdx.x;

    if (tid < 49) {
        const float by1 = boxes[4 * n + 0];
        const float bx1 = boxes[4 * n + 1];
        const float by2 = boxes[4 * n + 2];
        const float bx2 = boxes[4 * n + 3];
        const float h = by2 - by1;
        const float w = bx2 - bx1;
        float rl = 4.0f + log2f(sqrtf(h * w) / 0.21875f);
        int level = (int)rintf(rl);            // round-half-even = jnp.round
        level = min(5, max(2, level));
        const int H = 256 >> (level - 2);
        const int W = H;
        const int py = tid / 7;
        const int px = tid - 7 * py;

        // y interp
        const float ty = (float)py / 6.0f;
        const float ys = (by1 + ty * (by2 - by1)) * (float)(H - 1);
        const float yf = floorf(ys);
        const float ly = ys - yf;
        int y0 = (int)yf; y0 = min(H - 1, max(0, y0));
        const int y1 = min(H - 1, y0 + 1);
        const float vy = (ys >= 0.0f && ys <= (float)(H - 1)) ? 1.0f : 0.0f;

        // x interp
        const float tx = (float)px / 6.0f;
        const float xs = (bx1 + tx * (bx2 - bx1)) * (float)(W - 1);
        const float xf = floorf(xs);
        const float lx = xs - xf;
        int x0 = (int)xf; x0 = min(W - 1, max(0, x0));
        const float vx = (xs >= 0.0f && xs <= (float)(W - 1)) ? 1.0f : 0.0f;
        const int xb = min(x0, W - 2);         // float2 base column
        const bool edge = (x0 != xb);
        const float a = edge ? 0.0f : vx * (1.0f - lx);
        const float b = edge ? vx : vx * lx;

        // x window endpoints (tx=0,1), identical on every thread
        const float xsA = bx1 * (float)(W - 1);
        int xA = (int)floorf(xsA); xA = min(W - 1, max(0, xA));
        const int xbA = min(xA, W - 2);
        const float xsB = bx2 * (float)(W - 1);
        int xB = (int)floorf(xsB); xB = min(W - 1, max(0, xB));
        const int xbB = min(xB, W - 2);
        const int xb0  = xbA & ~3;                // 16B-aligned window start
        const int need = xbB + 2 - xb0;           // cols needed from xb0
        const int sa4  = (need + 3) >> 2;         // float4s/row

        s_off0[tid] = y0 * W + xb;
        s_off1[tid] = y1 * W + xb;
        s_a[tid] = a;
        s_b[tid] = b;
        s_w0[tid] = vy * (1.0f - ly);
        s_w1[tid] = vy * ly;
        s_dx[tid] = xb - xb0;
        if (px == 0) {
            s_rowoff[2 * py]     = y0 * W;
            s_rowoff[2 * py + 1] = y1 * W;
        }
        if (tid == 0) {
            s_HW   = H * W;
            s_fmap = (level == 2) ? p2 : (level == 3) ? p3 : (level == 4) ? p4 : p5;
            s_xb0  = xb0;
            s_sel  = (need <= 28) ? (sa4 | 1) : 0;   // 1/3/5/7 fast, 0 fallback
        }
    }
    __syncthreads();                 // the only block-wide barrier

    const int HW = s_HW;
    const float* __restrict__ lvl = s_fmap;
    const int lane = tid & 63;
    const int wave = tid >> 6;
    const int sel  = s_sel;

    if (sel) {
        const int chw = eighth * ECH + wave * WCH;       // wave's first channel
        const unsigned cb0 = (unsigned)chw * (unsigned)HW;
        const unsigned lim = (unsigned)(NCH * HW - 4);
        float* buf0 = &s_stage[wave][0][0];
        float* buf1 = &s_stage[wave][1][0];
        float* __restrict__ opw =
            out + (size_t)n * ELEMS_PER_BOX + (size_t)chw * 49;

        if (sel == 3)
            fast_steps<3>(lvl, opw, buf0, buf1, lane, HW, cb0, lim, s_xb0,
                          s_rowoff, s_dx, s_a, s_b, s_w0, s_w1);
        else if (sel == 5)
            fast_steps<5>(lvl, opw, buf0, buf1, lane, HW, cb0, lim, s_xb0,
                          s_rowoff, s_dx, s_a, s_b, s_w0, s_w1);
        else if (sel == 7)
            fast_steps<7>(lvl, opw, buf0, buf1, lane, HW, cb0, lim, s_xb0,
                          s_rowoff, s_dx, s_a, s_b, s_w0, s_w1);
        else
            fast_steps<1>(lvl, opw, buf0, buf1, lane, HW, cb0, lim, s_xb0,
                          s_rowoff, s_dx, s_a, s_b, s_w0, s_w1);
    } else {
        // wide-x-window fallback: proven R3-style float2 gathers, 128 threads,
        // 8 groups of 4 channels (196 outputs = 128 + 68 per group)
        const int c1  = tid / 49,  p1  = tid - 49 * c1;
        const int o2  = 128 + tid;
        const int o2c = o2 < STEPOUT ? o2 : STEPOUT - 1;
        const int c2  = o2c / 49,  p2i = o2c - 49 * c2;
        const bool act2 = (tid < STEPOUT - 128);

        const float a1 = s_a[p1],  b1 = s_b[p1],  w01f = s_w0[p1],  w11f = s_w1[p1];
        const float a2 = s_a[p2i], b2 = s_b[p2i], w02f = s_w0[p2i], w12f = s_w1[p2i];
        const int off01 = s_off0[p1],  off11 = s_off1[p1];
        const int off02 = s_off0[p2i], off12 = s_off1[p2i];

        const float* __restrict__ fbase = lvl + (size_t)(eighth * ECH) * HW;
        float* __restrict__ op =
            out + (size_t)n * ELEMS_PER_BOX + (size_t)(eighth * ECH) * 49;
        for (int g = 0; g < 8; ++g) {
            const float* pl1 = fbase + (size_t)(g * SCH + c1) * HW;
            const f2 q0 = *(const f2*)(pl1 + off01);
            const f2 q1 = *(const f2*)(pl1 + off11);
            const float r0 = q0.x * a1 + q0.y * b1;
            const float r1 = q1.x * a1 + q1.y * b1;
            op[g * STEPOUT + tid] = r0 * w01f + r1 * w11f;
            if (act2) {
                const float* pl2 = fbase + (size_t)(g * SCH + c2) * HW;
                const f2 u0 = *(const f2*)(pl2 + off02);
                const f2 u1 = *(const f2*)(pl2 + off12);
                const float s0 = u0.x * a2 + u0.y * b2;
                const float s1 = u1.x * a2 + u1.y * b2;
                op[g * STEPOUT + 128 + tid] = s0 * w02f + s1 * w12f;
            }
        }
    }
}

extern "C" void kernel_launch(void* const* d_in, const int* in_sizes, int n_in,
                              void* d_out, int out_size, void* d_ws, size_t ws_size,
                              hipStream_t stream) {
    const float* boxes = (const float*)d_in[0];
    const float* p2    = (const float*)d_in[1];
    const float* p3    = (const float*)d_in[2];
    const float* p4    = (const float*)d_in[3];
    const float* p5    = (const float*)d_in[4];
    float* out = (float*)d_out;
    const int N = in_sizes[0] / 4;

    roi_align_kernel<<<N * 8, 128, 0, stream>>>(boxes, p2, p3, p4, p5, out, N);
}